// Round 1
// baseline (639.907 us; speedup 1.0000x reference)
//
#include <hip/hip_runtime.h>

#define C 128
#define INV_SQRT2 0.7071067811865476f

// ---------------- CSR build ----------------

__global__ void k_count(const int* __restrict__ col, int E, int* __restrict__ deg) {
    int e = blockIdx.x * 256 + threadIdx.x;
    if (e < E) atomicAdd(&deg[col[e]], 1);
}

__global__ void k_chunk_sum(const int* __restrict__ deg, int N, int* __restrict__ partial) {
    __shared__ int s[256];
    int i = blockIdx.x * 256 + threadIdx.x;
    int t = threadIdx.x;
    s[t] = (i < N) ? deg[i] : 0;
    __syncthreads();
    for (int off = 128; off > 0; off >>= 1) {
        if (t < off) s[t] += s[t + off];
        __syncthreads();
    }
    if (t == 0) partial[blockIdx.x] = s[0];
}

// single block, 512 threads: exclusive scan of chunk partials (nchunks <= 512)
__global__ void k_scan_partials(int* __restrict__ partial, int nchunks,
                                int* __restrict__ row_start, int N, int E) {
    __shared__ int s[512];
    int t = threadIdx.x;
    int v = (t < nchunks) ? partial[t] : 0;
    s[t] = v;
    __syncthreads();
    for (int off = 1; off < 512; off <<= 1) {
        int add = (t >= off) ? s[t - off] : 0;
        __syncthreads();
        s[t] += add;
        __syncthreads();
    }
    if (t < nchunks) partial[t] = s[t] - v;  // exclusive chunk offset
    if (t == 0) row_start[N] = E;
}

__global__ void k_chunk_scan(const int* __restrict__ deg, const int* __restrict__ chunk_off,
                             int N, int* __restrict__ row_start) {
    __shared__ int s[256];
    int i = blockIdx.x * 256 + threadIdx.x;
    int t = threadIdx.x;
    int v = (i < N) ? deg[i] : 0;
    s[t] = v;
    __syncthreads();
    for (int off = 1; off < 256; off <<= 1) {
        int add = (t >= off) ? s[t - off] : 0;
        __syncthreads();
        s[t] += add;
        __syncthreads();
    }
    if (i < N) row_start[i] = chunk_off[blockIdx.x] + s[t] - v;
}

__global__ void k_fill(const int* __restrict__ row, const int* __restrict__ col, int E,
                       const int* __restrict__ row_start, int* __restrict__ cursor,
                       int* __restrict__ src_sorted) {
    int e = blockIdx.x * 256 + threadIdx.x;
    if (e < E) {
        int v = col[e];
        int p = atomicAdd(&cursor[v], 1);
        src_sorted[row_start[v] + p] = row[e];
    }
}

// ---------------- aggregation: agg[n] = deg^-1/2 * sum_{e: col=n} x[row_e] ----------------

__global__ __launch_bounds__(128) void k_aggregate(
    const float* __restrict__ x, const int* __restrict__ row_start,
    const int* __restrict__ src_sorted, float* __restrict__ agg, int N)
{
    int n = blockIdx.x;
    if (n >= N) return;
    int t = threadIdx.x;  // channel 0..127
    int s0 = row_start[n], s1 = row_start[n + 1];
    float acc0 = 0.f, acc1 = 0.f;
    int j = s0;
    for (; j + 1 < s1; j += 2) {
        int a = src_sorted[j];
        int b = src_sorted[j + 1];
        acc0 += x[(long)a * C + t];
        acc1 += x[(long)b * C + t];
    }
    if (j < s1) acc0 += x[(long)src_sorted[j] * C + t];
    float d = (s1 > s0) ? rsqrtf((float)(s1 - s0)) : 0.f;
    agg[(long)n * C + t] = (acc0 + acc1) * d;
}

// ---------------- weight normalization: WT[c][i], c<128: mpw_res[i][c]; c>=128: mpw_neigh[i][c-128] ----------------

__global__ void k_weights(const float* __restrict__ w_res, const float* __restrict__ w_neigh,
                          float* __restrict__ WT) {
    int r = blockIdx.x;        // 0..255
    int mtx = r >> 7;          // 0: res, 1: neigh
    int i = r & 127;           // weight row (output channel)
    const float* w = mtx ? w_neigh : w_res;
    int t = threadIdx.x;       // 0..63
    float a = w[i * C + t];
    float b = w[i * C + t + 64];
    float ss = a * a + b * b;
    #pragma unroll
    for (int off = 32; off > 0; off >>= 1) ss += __shfl_down(ss, off);
    ss = __shfl(ss, 0);
    float norm = sqrtf(ss);
    float denom = 1e-4f + norm * 0.08838834764831845f;   // eps + norm/sqrt(128)
    float scale = 1.0f / (denom * 11.313708498984761f);  // /denom /sqrt(128)
    WT[(mtx * C + t) * C + i]      = a * scale;
    WT[(mtx * C + t + 64) * C + i] = b * scale;
}

// ---------------- fused GEMM: out = mask * ([x | agg] @ [Wres|Wneigh]^T) ----------------
// block = 128 threads: j = tid&63 (cols j and j+64), g = tid>>6 (node half-tile)
// block covers 32 nodes x 128 cols; per-thread 16 nodes x 2 cols.
// x/agg read as wave-uniform broadcast float4 (each value read once per wave).

__global__ __launch_bounds__(128) void k_gemm(
    const float* __restrict__ x, const float* __restrict__ agg,
    const float* __restrict__ WT, const int* __restrict__ row_start,
    float* __restrict__ out, int N)
{
    int j = threadIdx.x & 63;
    int g = threadIdx.x >> 6;
    long n0 = (long)blockIdx.x * 32 + g * 16;
    if (n0 >= N) return;

    float acc0[16], acc1[16];
    #pragma unroll
    for (int m = 0; m < 16; m++) { acc0[m] = 0.f; acc1[m] = 0.f; }

    const float4* A0 = (const float4*)(x + n0 * C);
    const float4* A1 = (const float4*)(agg + n0 * C);

    #pragma unroll 1
    for (int half = 0; half < 2; half++) {
        const float4* A = half ? A1 : A0;
        const float* W = WT + half * C * C;
        #pragma unroll 1
        for (int c4 = 0; c4 < 32; c4++) {
            const float* wc = W + 4 * c4 * C;
            float w0a = wc[j],            w1a = wc[C + j];
            float w2a = wc[2 * C + j],    w3a = wc[3 * C + j];
            float w0b = wc[j + 64],       w1b = wc[C + j + 64];
            float w2b = wc[2 * C + j + 64], w3b = wc[3 * C + j + 64];
            #pragma unroll
            for (int m = 0; m < 16; m++) {
                float4 xv = A[m * 32 + c4];
                acc0[m] += xv.x * w0a + xv.y * w1a + xv.z * w2a + xv.w * w3a;
                acc1[m] += xv.x * w0b + xv.y * w1b + xv.z * w2b + xv.w * w3b;
            }
        }
    }

    #pragma unroll
    for (int m = 0; m < 16; m++) {
        long n = n0 + m;
        float sc = (row_start[n + 1] > row_start[n]) ? INV_SQRT2 : 1.0f;
        out[n * C + j]      = acc0[m] * sc;
        out[n * C + j + 64] = acc1[m] * sc;
    }
}

// ---------------- host ----------------

extern "C" void kernel_launch(void* const* d_in, const int* in_sizes, int n_in,
                              void* d_out, int out_size, void* d_ws, size_t ws_size,
                              hipStream_t stream) {
    const float* x       = (const float*)d_in[0];
    const int*   eidx    = (const int*)d_in[1];
    const float* w_neigh = (const float*)d_in[2];
    const float* w_res   = (const float*)d_in[3];
    float* out = (float*)d_out;

    int N = in_sizes[0] / C;
    int E = in_sizes[1] / 2;
    const int* row = eidx;        // edge_index[0] = source
    const int* col = eidx + E;    // edge_index[1] = target

    char* ws = (char*)d_ws;
    size_t off = 0;
    auto alloc = [&](size_t bytes) {
        size_t o = off;
        off += (bytes + 511) & ~(size_t)511;
        return o;
    };
    int*   deg        = (int*)(ws + alloc((size_t)N * 4));
    int*   cursor     = (int*)(ws + alloc((size_t)N * 4));
    int*   row_start  = (int*)(ws + alloc((size_t)(N + 1) * 4));
    int*   partial    = (int*)(ws + alloc(512 * 4));
    int*   src_sorted = (int*)(ws + alloc((size_t)E * 4));
    float* WT         = (float*)(ws + alloc((size_t)256 * C * 4));
    float* agg        = (float*)(ws + alloc((size_t)N * C * 4));
    (void)ws_size;

    hipMemsetAsync(deg, 0, (size_t)N * 4, stream);
    hipMemsetAsync(cursor, 0, (size_t)N * 4, stream);

    int eblocks = (E + 255) / 256;
    int nchunks = (N + 255) / 256;  // 391 for N=100000, fits single-block scan (<=512)

    k_count<<<eblocks, 256, 0, stream>>>(col, E, deg);
    k_chunk_sum<<<nchunks, 256, 0, stream>>>(deg, N, partial);
    k_scan_partials<<<1, 512, 0, stream>>>(partial, nchunks, row_start, N, E);
    k_chunk_scan<<<nchunks, 256, 0, stream>>>(deg, partial, N, row_start);
    k_fill<<<eblocks, 256, 0, stream>>>(row, col, E, row_start, cursor, src_sorted);
    k_aggregate<<<N, 128, 0, stream>>>(x, row_start, src_sorted, agg, N);
    k_weights<<<256, 64, 0, stream>>>(w_res, w_neigh, WT);
    k_gemm<<<(N + 31) / 32, 128, 0, stream>>>(x, agg, WT, row_start, out, N);
}

// Round 2
// 415.079 us; speedup vs baseline: 1.5416x; 1.5416x over previous
//
#include <hip/hip_runtime.h>
#include <hip/hip_bf16.h>

#define C 128
#define INV_SQRT2 0.7071067811865476f

typedef __attribute__((ext_vector_type(8))) short short8;
typedef __attribute__((ext_vector_type(4))) float f32x4;

__device__ inline ushort f2b(float f) {
    __hip_bfloat16 h = __float2bfloat16(f);
    return __builtin_bit_cast(ushort, h);
}

// ---------------- CSR build ----------------

__global__ void k_count(const int* __restrict__ col, int E, int* __restrict__ deg) {
    int e = blockIdx.x * 256 + threadIdx.x;
    if (e < E) atomicAdd(&deg[col[e]], 1);
}

__global__ void k_chunk_sum(const int* __restrict__ deg, int N, int* __restrict__ partial) {
    __shared__ int s[256];
    int i = blockIdx.x * 256 + threadIdx.x;
    int t = threadIdx.x;
    s[t] = (i < N) ? deg[i] : 0;
    __syncthreads();
    for (int off = 128; off > 0; off >>= 1) {
        if (t < off) s[t] += s[t + off];
        __syncthreads();
    }
    if (t == 0) partial[blockIdx.x] = s[0];
}

__global__ void k_scan_partials(int* __restrict__ partial, int nchunks,
                                int* __restrict__ row_start, int N, int E) {
    __shared__ int s[512];
    int t = threadIdx.x;
    int v = (t < nchunks) ? partial[t] : 0;
    s[t] = v;
    __syncthreads();
    for (int off = 1; off < 512; off <<= 1) {
        int add = (t >= off) ? s[t - off] : 0;
        __syncthreads();
        s[t] += add;
        __syncthreads();
    }
    if (t < nchunks) partial[t] = s[t] - v;
    if (t == 0) row_start[N] = E;
}

__global__ void k_chunk_scan(const int* __restrict__ deg, const int* __restrict__ chunk_off,
                             int N, int* __restrict__ row_start) {
    __shared__ int s[256];
    int i = blockIdx.x * 256 + threadIdx.x;
    int t = threadIdx.x;
    int v = (i < N) ? deg[i] : 0;
    s[t] = v;
    __syncthreads();
    for (int off = 1; off < 256; off <<= 1) {
        int add = (t >= off) ? s[t - off] : 0;
        __syncthreads();
        s[t] += add;
        __syncthreads();
    }
    if (i < N) row_start[i] = chunk_off[blockIdx.x] + s[t] - v;
}

__global__ void k_fill(const int* __restrict__ row, const int* __restrict__ col, int E,
                       const int* __restrict__ row_start, int* __restrict__ cursor,
                       int* __restrict__ src_sorted) {
    int e = blockIdx.x * 256 + threadIdx.x;
    if (e < E) {
        int v = col[e];
        int p = atomicAdd(&cursor[v], 1);
        src_sorted[row_start[v] + p] = row[e];
    }
}

// ---------------- cast x -> bf16 ----------------

__global__ __launch_bounds__(256) void k_cast(const float4* __restrict__ x,
                                              ushort* __restrict__ xb, int n4) {
    int i = blockIdx.x * 256 + threadIdx.x;
    if (i < n4) {
        float4 v = x[i];
        ushort4 o;
        o.x = f2b(v.x); o.y = f2b(v.y); o.z = f2b(v.z); o.w = f2b(v.w);
        *(ushort4*)(xb + (size_t)i * 4) = o;
    }
}

// ---------------- aggregation: aggb[n] = deg^-1/2 * sum x_bf16[src] ----------------
// one wave per node; lane owns channels 2t, 2t+1 (packed uint loads)

__global__ __launch_bounds__(256) void k_aggregate(
    const ushort* __restrict__ xb, const int* __restrict__ row_start,
    const int* __restrict__ src_sorted, ushort* __restrict__ aggb, int N)
{
    int node = blockIdx.x * 4 + (threadIdx.x >> 6);
    if (node >= N) return;
    int t = threadIdx.x & 63;
    int s0 = row_start[node], s1 = row_start[node + 1];
    float a0 = 0.f, a1 = 0.f, b0 = 0.f, b1 = 0.f;
    int j = s0;
    for (; j + 1 < s1; j += 2) {
        int sa = src_sorted[j];
        int sb = src_sorted[j + 1];
        uint va = *(const uint*)(xb + (size_t)sa * C + 2 * t);
        uint vb = *(const uint*)(xb + (size_t)sb * C + 2 * t);
        a0 += __builtin_bit_cast(float, va << 16);
        a1 += __builtin_bit_cast(float, va & 0xffff0000u);
        b0 += __builtin_bit_cast(float, vb << 16);
        b1 += __builtin_bit_cast(float, vb & 0xffff0000u);
    }
    if (j < s1) {
        uint va = *(const uint*)(xb + (size_t)src_sorted[j] * C + 2 * t);
        a0 += __builtin_bit_cast(float, va << 16);
        a1 += __builtin_bit_cast(float, va & 0xffff0000u);
    }
    float d = (s1 > s0) ? rsqrtf((float)(s1 - s0)) : 0.f;
    uint lo = f2b((a0 + b0) * d);
    uint hi = f2b((a1 + b1) * d);
    *(uint*)(aggb + (size_t)node * C + 2 * t) = lo | (hi << 16);
}

// ---------------- weight normalize + pack into B-fragment layout ----------------
// Bp[(g)*128 + n][j] with g = h*16 + (c>>3), j = c&7 ; value = wn_h[n][c]
// (so a GEMM B-frag load at (kk,quad,n) reads 8 contiguous bf16)

__global__ void k_weights(const float* __restrict__ w_res, const float* __restrict__ w_neigh,
                          ushort* __restrict__ Bp) {
    int r = blockIdx.x;        // 0..255
    int h = r >> 7;            // 0: res, 1: neigh
    int i = r & 127;           // output channel n
    const float* w = h ? w_neigh : w_res;
    int t = threadIdx.x;       // 0..63
    float a = w[i * C + t];
    float b = w[i * C + t + 64];
    float ss = a * a + b * b;
    #pragma unroll
    for (int off = 32; off > 0; off >>= 1) ss += __shfl_down(ss, off);
    ss = __shfl(ss, 0);
    float norm = sqrtf(ss);
    float denom = 1e-4f + norm * 0.08838834764831845f;   // eps + norm/sqrt(128)
    float scale = 1.0f / (denom * 11.313708498984761f);  // /denom /sqrt(128)
    int c1 = t, c2 = t + 64;
    Bp[(size_t)(h * 16 + (c1 >> 3)) * 1024 + i * 8 + (c1 & 7)] = f2b(a * scale);
    Bp[(size_t)(h * 16 + (c2 >> 3)) * 1024 + i * 8 + (c2 & 7)] = f2b(b * scale);
}

// ---------------- MFMA GEMM: out = mask * ([xb | aggb] @ [Wres|Wneigh]^T) ----------------
// block = 256 threads (4 waves, 2x2 wave grid), 128 nodes x 128 cols per block.
// wave: 64 nodes x 64 cols = 4x4 grid of 16x16 tiles, K=256 in 8 steps of 32.

__global__ __launch_bounds__(256) void k_gemm_mfma(
    const ushort* __restrict__ xb, const ushort* __restrict__ aggb,
    const ushort* __restrict__ Bp, const int* __restrict__ deg,
    float* __restrict__ out, int N)
{
    int wave = threadIdx.x >> 6;
    int lane = threadIdx.x & 63;
    int quad = lane >> 4;
    int l16  = lane & 15;
    int wm = wave & 1, wn = wave >> 1;
    long n0 = (long)blockIdx.x * 128 + wm * 64;
    int  c0 = wn * 64;

    f32x4 acc[4][4];
    #pragma unroll
    for (int mt = 0; mt < 4; mt++)
        #pragma unroll
        for (int nt = 0; nt < 4; nt++)
            acc[mt][nt] = (f32x4){0.f, 0.f, 0.f, 0.f};

    #pragma unroll
    for (int kk = 0; kk < 8; kk++) {
        const ushort* A = (kk < 4) ? xb : aggb;
        int k0 = (kk & 3) * 32;
        short8 af[4], bf[4];
        #pragma unroll
        for (int mt = 0; mt < 4; mt++) {
            long rrow = n0 + mt * 16 + l16;
            if (rrow >= N) rrow = N - 1;   // clamp; garbage rows never stored
            af[mt] = *(const short8*)(A + rrow * C + k0 + quad * 8);
        }
        #pragma unroll
        for (int nt = 0; nt < 4; nt++) {
            int n = c0 + nt * 16 + l16;
            bf[nt] = *(const short8*)(Bp + ((size_t)(kk * 4 + quad) * 128 + n) * 8);
        }
        #pragma unroll
        for (int mt = 0; mt < 4; mt++)
            #pragma unroll
            for (int nt = 0; nt < 4; nt++)
                acc[mt][nt] = __builtin_amdgcn_mfma_f32_16x16x32_bf16(
                    af[mt], bf[nt], acc[mt][nt], 0, 0, 0);
    }

    // epilogue: D col = l16, row = quad*4 + r
    #pragma unroll
    for (int mt = 0; mt < 4; mt++) {
        long rbase = n0 + mt * 16 + quad * 4;
        #pragma unroll
        for (int r = 0; r < 4; r++) {
            long row = rbase + r;
            if (row < N) {
                float sc = deg[row] > 0 ? INV_SQRT2 : 1.0f;
                float* o = out + row * C + c0 + l16;
                #pragma unroll
                for (int nt = 0; nt < 4; nt++)
                    o[nt * 16] = acc[mt][nt][r] * sc;
            }
        }
    }
}

// ---------------- host ----------------

extern "C" void kernel_launch(void* const* d_in, const int* in_sizes, int n_in,
                              void* d_out, int out_size, void* d_ws, size_t ws_size,
                              hipStream_t stream) {
    const float* x       = (const float*)d_in[0];
    const int*   eidx    = (const int*)d_in[1];
    const float* w_neigh = (const float*)d_in[2];
    const float* w_res   = (const float*)d_in[3];
    float* out = (float*)d_out;

    int N = in_sizes[0] / C;
    int E = in_sizes[1] / 2;
    const int* row = eidx;        // edge_index[0] = source
    const int* col = eidx + E;    // edge_index[1] = target

    char* ws = (char*)d_ws;
    size_t off = 0;
    auto alloc = [&](size_t bytes) {
        size_t o = off;
        off += (bytes + 511) & ~(size_t)511;
        return o;
    };
    int*    deg        = (int*)(ws + alloc((size_t)N * 4));
    int*    cursor     = (int*)(ws + alloc((size_t)N * 4));
    int*    row_start  = (int*)(ws + alloc((size_t)(N + 1) * 4));
    int*    partial    = (int*)(ws + alloc(512 * 4));
    int*    src_sorted = (int*)(ws + alloc((size_t)E * 4));
    ushort* Bp         = (ushort*)(ws + alloc((size_t)32 * 1024 * 2));
    ushort* xb         = (ushort*)(ws + alloc((size_t)N * C * 2));
    ushort* aggb       = (ushort*)(ws + alloc((size_t)N * C * 2));
    (void)ws_size;

    hipMemsetAsync(deg, 0, (size_t)N * 4, stream);
    hipMemsetAsync(cursor, 0, (size_t)N * 4, stream);

    int eblocks = (E + 255) / 256;
    int nchunks = (N + 255) / 256;  // 391 for N=100000, fits single-block scan

    k_count<<<eblocks, 256, 0, stream>>>(col, E, deg);
    k_chunk_sum<<<nchunks, 256, 0, stream>>>(deg, N, partial);
    k_scan_partials<<<1, 512, 0, stream>>>(partial, nchunks, row_start, N, E);
    k_chunk_scan<<<nchunks, 256, 0, stream>>>(deg, partial, N, row_start);
    k_fill<<<eblocks, 256, 0, stream>>>(row, col, E, row_start, cursor, src_sorted);

    int n4 = N * C / 4;
    k_cast<<<(n4 + 255) / 256, 256, 0, stream>>>((const float4*)x, xb, n4);
    k_aggregate<<<(N + 3) / 4, 256, 0, stream>>>(xb, row_start, src_sorted, aggb, N);
    k_weights<<<256, 64, 0, stream>>>(w_res, w_neigh, Bp);
    k_gemm_mfma<<<(N + 127) / 128, 256, 0, stream>>>(xb, aggb, Bp, deg, out, N);
}

// Round 3
// 253.923 us; speedup vs baseline: 2.5201x; 1.6347x over previous
//
#include <hip/hip_runtime.h>
#include <hip/hip_bf16.h>

#define C 128
#define INV_SQRT2 0.7071067811865476f
#define NB 512          // radix buckets (col >> 8), 391 used for N=100000
#define EPB 8192        // edges per partition block

typedef __attribute__((ext_vector_type(8))) short short8;
typedef __attribute__((ext_vector_type(4))) float f32x4;

__device__ inline ushort f2b(float f) {
    __hip_bfloat16 h = __float2bfloat16(f);
    return __builtin_bit_cast(ushort, h);
}

// ---------------- P1a: per-block bucket histogram ----------------

__global__ __launch_bounds__(512) void k_hist(const int* __restrict__ col, int E,
                                              int* __restrict__ counts_g) {
    __shared__ int hist[NB];
    int t = threadIdx.x;
    hist[t] = 0;
    __syncthreads();
    int base = blockIdx.x * EPB;
    #pragma unroll
    for (int i = 0; i < EPB / 512; i++) {
        int e = base + i * 512 + t;
        if (e < E) atomicAdd(&hist[col[e] >> 8], 1);
    }
    __syncthreads();
    counts_g[blockIdx.x * NB + t] = hist[t];
}

// ---------------- P1b: per-bucket exclusive scan over blocks ----------------
// grid = NB blocks x 512 threads; nblk <= 512

__global__ __launch_bounds__(512) void k_scan_blocks(int* __restrict__ counts_g, int nblk,
                                                     int* __restrict__ totals) {
    __shared__ int s[512];
    int k = blockIdx.x;
    int t = threadIdx.x;
    int v = (t < nblk) ? counts_g[t * NB + k] : 0;
    s[t] = v;
    __syncthreads();
    for (int off = 1; off < 512; off <<= 1) {
        int add = (t >= off) ? s[t - off] : 0;
        __syncthreads();
        s[t] += add;
        __syncthreads();
    }
    if (t < nblk) counts_g[t * NB + k] = s[t] - v;   // exclusive over blocks
    if (t == 0) totals[k] = s[511];
}

// ---------------- P1b2: exclusive scan of bucket totals ----------------

__global__ __launch_bounds__(512) void k_scan_buckets(const int* __restrict__ totals,
                                                      int* __restrict__ bucketBase,
                                                      int* __restrict__ row_start,
                                                      int N, int E) {
    __shared__ int s[512];
    int t = threadIdx.x;
    int v = totals[t];
    s[t] = v;
    __syncthreads();
    for (int off = 1; off < 512; off <<= 1) {
        int add = (t >= off) ? s[t - off] : 0;
        __syncthreads();
        s[t] += add;
        __syncthreads();
    }
    bucketBase[t] = s[t] - v;
    if (t == 0) row_start[N] = E;
}

// ---------------- P1c: partition edges into bucket-contiguous records ----------------
// rec = ((col & 255) << 24) | row   (row < 2^24)

__global__ __launch_bounds__(512) void k_partition(
    const int* __restrict__ row, const int* __restrict__ col, int E,
    const int* __restrict__ counts_g, const int* __restrict__ bucketBase,
    unsigned int* __restrict__ recs)
{
    __shared__ int lbase[NB];
    __shared__ int rank[NB];
    int t = threadIdx.x;
    lbase[t] = bucketBase[t] + counts_g[blockIdx.x * NB + t];
    rank[t] = 0;
    __syncthreads();
    int base = blockIdx.x * EPB;
    #pragma unroll
    for (int i = 0; i < EPB / 512; i++) {
        int e = base + i * 512 + t;
        if (e < E) {
            int c = col[e];
            int k = c >> 8;
            int p = atomicAdd(&rank[k], 1);
            recs[lbase[k] + p] = ((unsigned int)(c & 255) << 24) | (unsigned int)row[e];
        }
    }
}

// ---------------- P2: per-bucket CSR fill (row_start + src_sorted) ----------------
// one block per bucket; scatter window ~= bucket edge count * 4B (~12.5 KB)

__global__ __launch_bounds__(256) void k_bucket_fill(
    const unsigned int* __restrict__ recs, const int* __restrict__ bucketBase,
    const int* __restrict__ totals, int N,
    int* __restrict__ row_start, int* __restrict__ src_sorted)
{
    __shared__ int hist[256];
    __shared__ int excl[256];
    __shared__ int cur[256];
    int k = blockIdx.x;
    int t = threadIdx.x;
    int base = bucketBase[k];
    int cnt  = totals[k];
    hist[t] = 0;
    __syncthreads();
    for (int i = t; i < cnt; i += 256)
        atomicAdd(&hist[recs[base + i] >> 24], 1);
    __syncthreads();
    int v = hist[t];
    int s = v;
    excl[t] = 0;  // reuse excl as scan buffer
    __syncthreads();
    // inclusive scan of hist into s via LDS
    excl[t] = v;
    __syncthreads();
    for (int off = 1; off < 256; off <<= 1) {
        int add = (t >= off) ? excl[t - off] : 0;
        __syncthreads();
        excl[t] += add;
        __syncthreads();
    }
    s = excl[t] - v;       // exclusive
    __syncthreads();
    excl[t] = s;
    cur[t] = s;
    int n = k * 256 + t;
    if (n < N) row_start[n] = base + s;
    __syncthreads();
    for (int i = t; i < cnt; i += 256) {
        unsigned int r = recs[base + i];
        int c = r >> 24;
        int p = atomicAdd(&cur[c], 1);
        src_sorted[base + p] = (int)(r & 0xFFFFFF);
    }
}

// ---------------- cast x -> bf16 ----------------

__global__ __launch_bounds__(256) void k_cast(const float4* __restrict__ x,
                                              ushort* __restrict__ xb, int n4) {
    int i = blockIdx.x * 256 + threadIdx.x;
    if (i < n4) {
        float4 v = x[i];
        ushort4 o;
        o.x = f2b(v.x); o.y = f2b(v.y); o.z = f2b(v.z); o.w = f2b(v.w);
        *(ushort4*)(xb + (size_t)i * 4) = o;
    }
}

// ---------------- aggregation: aggb[n] = deg^-1/2 * sum x_bf16[src] ----------------

__global__ __launch_bounds__(256) void k_aggregate(
    const ushort* __restrict__ xb, const int* __restrict__ row_start,
    const int* __restrict__ src_sorted, ushort* __restrict__ aggb, int N)
{
    int node = blockIdx.x * 4 + (threadIdx.x >> 6);
    if (node >= N) return;
    int t = threadIdx.x & 63;
    int s0 = row_start[node], s1 = row_start[node + 1];
    float a0 = 0.f, a1 = 0.f, b0 = 0.f, b1 = 0.f;
    float c0 = 0.f, c1 = 0.f, d0 = 0.f, d1 = 0.f;
    int j = s0;
    for (; j + 3 < s1; j += 4) {
        int sa = src_sorted[j];
        int sb = src_sorted[j + 1];
        int sc = src_sorted[j + 2];
        int sd = src_sorted[j + 3];
        uint va = *(const uint*)(xb + (size_t)sa * C + 2 * t);
        uint vb = *(const uint*)(xb + (size_t)sb * C + 2 * t);
        uint vc = *(const uint*)(xb + (size_t)sc * C + 2 * t);
        uint vd = *(const uint*)(xb + (size_t)sd * C + 2 * t);
        a0 += __builtin_bit_cast(float, va << 16);
        a1 += __builtin_bit_cast(float, va & 0xffff0000u);
        b0 += __builtin_bit_cast(float, vb << 16);
        b1 += __builtin_bit_cast(float, vb & 0xffff0000u);
        c0 += __builtin_bit_cast(float, vc << 16);
        c1 += __builtin_bit_cast(float, vc & 0xffff0000u);
        d0 += __builtin_bit_cast(float, vd << 16);
        d1 += __builtin_bit_cast(float, vd & 0xffff0000u);
    }
    for (; j < s1; j++) {
        uint va = *(const uint*)(xb + (size_t)src_sorted[j] * C + 2 * t);
        a0 += __builtin_bit_cast(float, va << 16);
        a1 += __builtin_bit_cast(float, va & 0xffff0000u);
    }
    float d = (s1 > s0) ? rsqrtf((float)(s1 - s0)) : 0.f;
    uint lo = f2b((a0 + b0 + c0 + d0) * d);
    uint hi = f2b((a1 + b1 + c1 + d1) * d);
    *(uint*)(aggb + (size_t)node * C + 2 * t) = lo | (hi << 16);
}

// ---------------- weight normalize + pack into B-fragment layout ----------------

__global__ void k_weights(const float* __restrict__ w_res, const float* __restrict__ w_neigh,
                          ushort* __restrict__ Bp) {
    int r = blockIdx.x;        // 0..255
    int h = r >> 7;            // 0: res, 1: neigh
    int i = r & 127;           // output channel n
    const float* w = h ? w_neigh : w_res;
    int t = threadIdx.x;       // 0..63
    float a = w[i * C + t];
    float b = w[i * C + t + 64];
    float ss = a * a + b * b;
    #pragma unroll
    for (int off = 32; off > 0; off >>= 1) ss += __shfl_down(ss, off);
    ss = __shfl(ss, 0);
    float norm = sqrtf(ss);
    float denom = 1e-4f + norm * 0.08838834764831845f;   // eps + norm/sqrt(128)
    float scale = 1.0f / (denom * 11.313708498984761f);  // /denom /sqrt(128)
    int c1 = t, c2 = t + 64;
    Bp[(size_t)(h * 16 + (c1 >> 3)) * 1024 + i * 8 + (c1 & 7)] = f2b(a * scale);
    Bp[(size_t)(h * 16 + (c2 >> 3)) * 1024 + i * 8 + (c2 & 7)] = f2b(b * scale);
}

// ---------------- MFMA GEMM: out = mask * ([xb | aggb] @ [Wres|Wneigh]^T) ----------------

__global__ __launch_bounds__(256) void k_gemm_mfma(
    const ushort* __restrict__ xb, const ushort* __restrict__ aggb,
    const ushort* __restrict__ Bp, const int* __restrict__ row_start,
    float* __restrict__ out, int N)
{
    int wave = threadIdx.x >> 6;
    int lane = threadIdx.x & 63;
    int quad = lane >> 4;
    int l16  = lane & 15;
    int wm = wave & 1, wn = wave >> 1;
    long n0 = (long)blockIdx.x * 128 + wm * 64;
    int  c0 = wn * 64;

    f32x4 acc[4][4];
    #pragma unroll
    for (int mt = 0; mt < 4; mt++)
        #pragma unroll
        for (int nt = 0; nt < 4; nt++)
            acc[mt][nt] = (f32x4){0.f, 0.f, 0.f, 0.f};

    #pragma unroll
    for (int kk = 0; kk < 8; kk++) {
        const ushort* A = (kk < 4) ? xb : aggb;
        int k0 = (kk & 3) * 32;
        short8 af[4], bf[4];
        #pragma unroll
        for (int mt = 0; mt < 4; mt++) {
            long rrow = n0 + mt * 16 + l16;
            if (rrow >= N) rrow = N - 1;   // clamp; garbage rows never stored
            af[mt] = *(const short8*)(A + rrow * C + k0 + quad * 8);
        }
        #pragma unroll
        for (int nt = 0; nt < 4; nt++) {
            int n = c0 + nt * 16 + l16;
            bf[nt] = *(const short8*)(Bp + ((size_t)(kk * 4 + quad) * 128 + n) * 8);
        }
        #pragma unroll
        for (int mt = 0; mt < 4; mt++)
            #pragma unroll
            for (int nt = 0; nt < 4; nt++)
                acc[mt][nt] = __builtin_amdgcn_mfma_f32_16x16x32_bf16(
                    af[mt], bf[nt], acc[mt][nt], 0, 0, 0);
    }

    #pragma unroll
    for (int mt = 0; mt < 4; mt++) {
        long rbase = n0 + mt * 16 + quad * 4;
        #pragma unroll
        for (int r = 0; r < 4; r++) {
            long row = rbase + r;
            if (row < N) {
                float sc = (row_start[row + 1] > row_start[row]) ? INV_SQRT2 : 1.0f;
                float* o = out + row * C + c0 + l16;
                #pragma unroll
                for (int nt = 0; nt < 4; nt++)
                    o[nt * 16] = acc[mt][nt][r] * sc;
            }
        }
    }
}

// ---------------- host ----------------

extern "C" void kernel_launch(void* const* d_in, const int* in_sizes, int n_in,
                              void* d_out, int out_size, void* d_ws, size_t ws_size,
                              hipStream_t stream) {
    const float* x       = (const float*)d_in[0];
    const int*   eidx    = (const int*)d_in[1];
    const float* w_neigh = (const float*)d_in[2];
    const float* w_res   = (const float*)d_in[3];
    float* out = (float*)d_out;

    int N = in_sizes[0] / C;
    int E = in_sizes[1] / 2;
    const int* row = eidx;        // edge_index[0] = source
    const int* col = eidx + E;    // edge_index[1] = target

    char* ws = (char*)d_ws;
    size_t off = 0;
    auto alloc = [&](size_t bytes) {
        size_t o = off;
        off += (bytes + 511) & ~(size_t)511;
        return o;
    };
    int nblk = (E + EPB - 1) / EPB;   // 196 for E=1.6M (must be <= 512)

    int*    row_start  = (int*)(ws + alloc((size_t)(N + 1) * 4));
    int*    counts_g   = (int*)(ws + alloc((size_t)nblk * NB * 4));
    int*    totals     = (int*)(ws + alloc(NB * 4));
    int*    bucketBase = (int*)(ws + alloc(NB * 4));
    unsigned int* recs = (unsigned int*)(ws + alloc((size_t)E * 4));
    int*    src_sorted = (int*)(ws + alloc((size_t)E * 4));
    ushort* Bp         = (ushort*)(ws + alloc((size_t)32 * 1024 * 2));
    ushort* xb         = (ushort*)(ws + alloc((size_t)N * C * 2));
    ushort* aggb       = (ushort*)(ws + alloc((size_t)N * C * 2));
    (void)ws_size;

    int nbuckets = (N + 255) >> 8;    // 391

    k_hist<<<nblk, 512, 0, stream>>>(col, E, counts_g);
    k_scan_blocks<<<NB, 512, 0, stream>>>(counts_g, nblk, totals);
    k_scan_buckets<<<1, 512, 0, stream>>>(totals, bucketBase, row_start, N, E);
    k_partition<<<nblk, 512, 0, stream>>>(row, col, E, counts_g, bucketBase, recs);
    k_bucket_fill<<<nbuckets, 256, 0, stream>>>(recs, bucketBase, totals, N, row_start, src_sorted);

    int n4 = N * C / 4;
    k_cast<<<(n4 + 255) / 256, 256, 0, stream>>>((const float4*)x, xb, n4);
    k_aggregate<<<(N + 3) / 4, 256, 0, stream>>>(xb, row_start, src_sorted, aggb, N);
    k_weights<<<256, 64, 0, stream>>>(w_res, w_neigh, Bp);
    k_gemm_mfma<<<(N + 127) / 128, 256, 0, stream>>>(xb, aggb, Bp, row_start, out, N);
}

// Round 4
// 240.677 us; speedup vs baseline: 2.6588x; 1.0550x over previous
//
#include <hip/hip_runtime.h>
#include <hip/hip_bf16.h>

#define C 128
#define INV_SQRT2 0.7071067811865476f
#define NB 512          // radix buckets (col >> 8), 391 used for N=100000
#define EPB 8192        // edges per partition block

typedef __attribute__((ext_vector_type(8))) short short8;
typedef __attribute__((ext_vector_type(4))) float f32x4;

__device__ inline ushort f2b(float f) {
    __hip_bfloat16 h = __float2bfloat16(f);
    return __builtin_bit_cast(ushort, h);
}

// ---------------- front kernel: bucket histogram | x->bf16 cast | weight pack ----------------

__global__ __launch_bounds__(512) void k_front(
    const int* __restrict__ col, int E, int* __restrict__ counts_g, int nblk,
    const float4* __restrict__ x, ushort* __restrict__ xb, int n4, int castBlocks,
    const float* __restrict__ w_res, const float* __restrict__ w_neigh,
    ushort* __restrict__ Bp)
{
    __shared__ int hist[NB];
    int b = blockIdx.x;
    int t = threadIdx.x;
    if (b < nblk) {
        // ---- histogram ----
        hist[t] = 0;
        __syncthreads();
        int base = b * EPB;
        #pragma unroll
        for (int i = 0; i < EPB / 512; i++) {
            int e = base + i * 512 + t;
            if (e < E) atomicAdd(&hist[col[e] >> 8], 1);
        }
        __syncthreads();
        counts_g[b * NB + t] = hist[t];
    } else if (b < nblk + castBlocks) {
        // ---- cast x -> bf16 ----
        int i = (b - nblk) * 512 + t;
        if (i < n4) {
            float4 v = x[i];
            ushort4 o;
            o.x = f2b(v.x); o.y = f2b(v.y); o.z = f2b(v.z); o.w = f2b(v.w);
            *(ushort4*)(xb + (size_t)i * 4) = o;
        }
    } else {
        // ---- weight normalize + pack into B-fragment layout ----
        int r = (b - nblk - castBlocks) * 8 + (t >> 6);   // 0..255
        int h = r >> 7;
        int i = r & 127;
        const float* w = h ? w_neigh : w_res;
        int lane = t & 63;
        float a = w[i * C + lane];
        float bb = w[i * C + lane + 64];
        float ss = a * a + bb * bb;
        #pragma unroll
        for (int off = 32; off > 0; off >>= 1) ss += __shfl_down(ss, off);
        ss = __shfl(ss, 0);
        float norm = sqrtf(ss);
        float denom = 1e-4f + norm * 0.08838834764831845f;   // eps + norm/sqrt(128)
        float scale = 1.0f / (denom * 11.313708498984761f);  // /denom /sqrt(128)
        int c1 = lane, c2 = lane + 64;
        Bp[(size_t)(h * 16 + (c1 >> 3)) * 1024 + i * 8 + (c1 & 7)] = f2b(a * scale);
        Bp[(size_t)(h * 16 + (c2 >> 3)) * 1024 + i * 8 + (c2 & 7)] = f2b(bb * scale);
    }
}

// ---------------- P1b: per-bucket exclusive scan over blocks ----------------

__global__ __launch_bounds__(512) void k_scan_blocks(int* __restrict__ counts_g, int nblk,
                                                     int* __restrict__ totals) {
    __shared__ int s[512];
    int k = blockIdx.x;
    int t = threadIdx.x;
    int v = (t < nblk) ? counts_g[t * NB + k] : 0;
    s[t] = v;
    __syncthreads();
    for (int off = 1; off < 512; off <<= 1) {
        int add = (t >= off) ? s[t - off] : 0;
        __syncthreads();
        s[t] += add;
        __syncthreads();
    }
    if (t < nblk) counts_g[t * NB + k] = s[t] - v;   // exclusive over blocks
    if (t == 0) totals[k] = s[511];
}

// ---------------- P1b2: exclusive scan of bucket totals ----------------

__global__ __launch_bounds__(512) void k_scan_buckets(const int* __restrict__ totals,
                                                      int* __restrict__ bucketBase,
                                                      int* __restrict__ row_start,
                                                      int N, int E) {
    __shared__ int s[512];
    int t = threadIdx.x;
    int v = totals[t];
    s[t] = v;
    __syncthreads();
    for (int off = 1; off < 512; off <<= 1) {
        int add = (t >= off) ? s[t - off] : 0;
        __syncthreads();
        s[t] += add;
        __syncthreads();
    }
    bucketBase[t] = s[t] - v;
    if (t == 0) row_start[N] = E;
}

// ---------------- P1c: partition edges into bucket-contiguous records ----------------

__global__ __launch_bounds__(512) void k_partition(
    const int* __restrict__ row, const int* __restrict__ col, int E,
    const int* __restrict__ counts_g, const int* __restrict__ bucketBase,
    unsigned int* __restrict__ recs)
{
    __shared__ int lbase[NB];
    __shared__ int rank[NB];
    int t = threadIdx.x;
    lbase[t] = bucketBase[t] + counts_g[blockIdx.x * NB + t];
    rank[t] = 0;
    __syncthreads();
    int base = blockIdx.x * EPB;
    #pragma unroll
    for (int i = 0; i < EPB / 512; i++) {
        int e = base + i * 512 + t;
        if (e < E) {
            int c = col[e];
            int k = c >> 8;
            int p = atomicAdd(&rank[k], 1);
            recs[lbase[k] + p] = ((unsigned int)(c & 255) << 24) | (unsigned int)row[e];
        }
    }
}

// ---------------- P2: per-bucket CSR fill (row_start + src_sorted) ----------------

__global__ __launch_bounds__(256) void k_bucket_fill(
    const unsigned int* __restrict__ recs, const int* __restrict__ bucketBase,
    const int* __restrict__ totals, int N,
    int* __restrict__ row_start, int* __restrict__ src_sorted)
{
    __shared__ int hist[256];
    __shared__ int excl[256];
    __shared__ int cur[256];
    int k = blockIdx.x;
    int t = threadIdx.x;
    int base = bucketBase[k];
    int cnt  = totals[k];
    hist[t] = 0;
    __syncthreads();
    for (int i = t; i < cnt; i += 256)
        atomicAdd(&hist[recs[base + i] >> 24], 1);
    __syncthreads();
    int v = hist[t];
    excl[t] = v;
    __syncthreads();
    for (int off = 1; off < 256; off <<= 1) {
        int add = (t >= off) ? excl[t - off] : 0;
        __syncthreads();
        excl[t] += add;
        __syncthreads();
    }
    int s = excl[t] - v;       // exclusive
    __syncthreads();
    cur[t] = s;
    int n = k * 256 + t;
    if (n < N) row_start[n] = base + s;
    __syncthreads();
    for (int i = t; i < cnt; i += 256) {
        unsigned int r = recs[base + i];
        int c = r >> 24;
        int p = atomicAdd(&cur[c], 1);
        src_sorted[base + p] = (int)(r & 0xFFFFFF);
    }
}

// ---------------- aggregation: aggb[n] = deg^-1/2 * sum x_bf16[src] ----------------
// one wave per node; 16 lanes per row (uint4 = 8 channels/lane), 4 edges per
// wave-instruction, 8 edges in flight per iteration. Cross edge-slot reduce
// via shfl_xor(16/32) once per node.

#define ACCUM(v) do { \
    acc[0] += __builtin_bit_cast(float, (v).x << 16); \
    acc[1] += __builtin_bit_cast(float, (v).x & 0xffff0000u); \
    acc[2] += __builtin_bit_cast(float, (v).y << 16); \
    acc[3] += __builtin_bit_cast(float, (v).y & 0xffff0000u); \
    acc[4] += __builtin_bit_cast(float, (v).z << 16); \
    acc[5] += __builtin_bit_cast(float, (v).z & 0xffff0000u); \
    acc[6] += __builtin_bit_cast(float, (v).w << 16); \
    acc[7] += __builtin_bit_cast(float, (v).w & 0xffff0000u); \
} while (0)

__global__ __launch_bounds__(256) void k_aggregate(
    const ushort* __restrict__ xb, const int* __restrict__ row_start,
    const int* __restrict__ src_sorted, ushort* __restrict__ aggb, int N)
{
    int node = blockIdx.x * 4 + (threadIdx.x >> 6);
    if (node >= N) return;
    int lane = threadIdx.x & 63;
    int sub = lane >> 4;       // edge slot 0..3
    int cl  = lane & 15;       // channel block: channels cl*8 .. cl*8+7
    int s0 = row_start[node], s1 = row_start[node + 1];

    float acc[8];
    #pragma unroll
    for (int i = 0; i < 8; i++) acc[i] = 0.f;

    for (int j = s0; j < s1; j += 8) {
        int jj0 = j + sub;
        int jj1 = j + 4 + sub;
        int i0 = src_sorted[jj0 < s1 ? jj0 : s1 - 1];
        int i1 = src_sorted[jj1 < s1 ? jj1 : s1 - 1];
        uint4 va = *(const uint4*)(xb + ((size_t)i0 << 7) + (cl << 3));
        uint4 vb = *(const uint4*)(xb + ((size_t)i1 << 7) + (cl << 3));
        if (jj0 >= s1) va = make_uint4(0, 0, 0, 0);
        if (jj1 >= s1) vb = make_uint4(0, 0, 0, 0);
        ACCUM(va);
        ACCUM(vb);
    }

    #pragma unroll
    for (int i = 0; i < 8; i++) {
        acc[i] += __shfl_xor(acc[i], 16);
        acc[i] += __shfl_xor(acc[i], 32);
    }

    float d = (s1 > s0) ? rsqrtf((float)(s1 - s0)) : 0.f;
    if (lane < 16) {
        uint4 o;
        o.x = (uint)f2b(acc[0] * d) | ((uint)f2b(acc[1] * d) << 16);
        o.y = (uint)f2b(acc[2] * d) | ((uint)f2b(acc[3] * d) << 16);
        o.z = (uint)f2b(acc[4] * d) | ((uint)f2b(acc[5] * d) << 16);
        o.w = (uint)f2b(acc[6] * d) | ((uint)f2b(acc[7] * d) << 16);
        *(uint4*)(aggb + ((size_t)node << 7) + (cl << 3)) = o;
    }
}

// ---------------- MFMA GEMM: out = mask * ([xb | aggb] @ [Wres|Wneigh]^T) ----------------

__global__ __launch_bounds__(256) void k_gemm_mfma(
    const ushort* __restrict__ xb, const ushort* __restrict__ aggb,
    const ushort* __restrict__ Bp, const int* __restrict__ row_start,
    float* __restrict__ out, int N)
{
    int wave = threadIdx.x >> 6;
    int lane = threadIdx.x & 63;
    int quad = lane >> 4;
    int l16  = lane & 15;
    int wm = wave & 1, wn = wave >> 1;
    long n0 = (long)blockIdx.x * 128 + wm * 64;
    int  c0 = wn * 64;

    f32x4 acc[4][4];
    #pragma unroll
    for (int mt = 0; mt < 4; mt++)
        #pragma unroll
        for (int nt = 0; nt < 4; nt++)
            acc[mt][nt] = (f32x4){0.f, 0.f, 0.f, 0.f};

    #pragma unroll
    for (int kk = 0; kk < 8; kk++) {
        const ushort* A = (kk < 4) ? xb : aggb;
        int k0 = (kk & 3) * 32;
        short8 af[4], bf[4];
        #pragma unroll
        for (int mt = 0; mt < 4; mt++) {
            long rrow = n0 + mt * 16 + l16;
            if (rrow >= N) rrow = N - 1;   // clamp; garbage rows never stored
            af[mt] = *(const short8*)(A + rrow * C + k0 + quad * 8);
        }
        #pragma unroll
        for (int nt = 0; nt < 4; nt++) {
            int n = c0 + nt * 16 + l16;
            bf[nt] = *(const short8*)(Bp + ((size_t)(kk * 4 + quad) * 128 + n) * 8);
        }
        #pragma unroll
        for (int mt = 0; mt < 4; mt++)
            #pragma unroll
            for (int nt = 0; nt < 4; nt++)
                acc[mt][nt] = __builtin_amdgcn_mfma_f32_16x16x32_bf16(
                    af[mt], bf[nt], acc[mt][nt], 0, 0, 0);
    }

    #pragma unroll
    for (int mt = 0; mt < 4; mt++) {
        long rbase = n0 + mt * 16 + quad * 4;
        #pragma unroll
        for (int r = 0; r < 4; r++) {
            long row = rbase + r;
            if (row < N) {
                float sc = (row_start[row + 1] > row_start[row]) ? INV_SQRT2 : 1.0f;
                float* o = out + row * C + c0 + l16;
                #pragma unroll
                for (int nt = 0; nt < 4; nt++)
                    __builtin_nontemporal_store(acc[mt][nt][r] * sc, &o[nt * 16]);
            }
        }
    }
}

// ---------------- host ----------------

extern "C" void kernel_launch(void* const* d_in, const int* in_sizes, int n_in,
                              void* d_out, int out_size, void* d_ws, size_t ws_size,
                              hipStream_t stream) {
    const float* x       = (const float*)d_in[0];
    const int*   eidx    = (const int*)d_in[1];
    const float* w_neigh = (const float*)d_in[2];
    const float* w_res   = (const float*)d_in[3];
    float* out = (float*)d_out;

    int N = in_sizes[0] / C;
    int E = in_sizes[1] / 2;
    const int* row = eidx;        // edge_index[0] = source
    const int* col = eidx + E;    // edge_index[1] = target

    char* ws = (char*)d_ws;
    size_t off = 0;
    auto alloc = [&](size_t bytes) {
        size_t o = off;
        off += (bytes + 511) & ~(size_t)511;
        return o;
    };
    int nblk = (E + EPB - 1) / EPB;   // 196 for E=1.6M (must be <= 512)

    int*    row_start  = (int*)(ws + alloc((size_t)(N + 1) * 4));
    int*    counts_g   = (int*)(ws + alloc((size_t)nblk * NB * 4));
    int*    totals     = (int*)(ws + alloc(NB * 4));
    int*    bucketBase = (int*)(ws + alloc(NB * 4));
    unsigned int* recs = (unsigned int*)(ws + alloc((size_t)E * 4));
    int*    src_sorted = (int*)(ws + alloc((size_t)E * 4));
    ushort* Bp         = (ushort*)(ws + alloc((size_t)32 * 1024 * 2));
    ushort* xb         = (ushort*)(ws + alloc((size_t)N * C * 2));
    ushort* aggb       = (ushort*)(ws + alloc((size_t)N * C * 2));
    (void)ws_size;

    int nbuckets = (N + 255) >> 8;    // 391
    int n4 = N * C / 4;
    int castBlocks = (n4 + 511) / 512;

    k_front<<<nblk + castBlocks + 32, 512, 0, stream>>>(
        col, E, counts_g, nblk, (const float4*)x, xb, n4, castBlocks,
        w_res, w_neigh, Bp);
    k_scan_blocks<<<NB, 512, 0, stream>>>(counts_g, nblk, totals);
    k_scan_buckets<<<1, 512, 0, stream>>>(totals, bucketBase, row_start, N, E);
    k_partition<<<nblk, 512, 0, stream>>>(row, col, E, counts_g, bucketBase, recs);
    k_bucket_fill<<<nbuckets, 256, 0, stream>>>(recs, bucketBase, totals, N, row_start, src_sorted);
    k_aggregate<<<(N + 3) / 4, 256, 0, stream>>>(xb, row_start, src_sorted, aggb, N);
    k_gemm_mfma<<<(N + 127) / 128, 256, 0, stream>>>(xb, aggb, Bp, row_start, out, N);
}